// Round 1
// baseline (1570.543 us; speedup 1.0000x reference)
//
#include <hip/hip_runtime.h>
#include <math.h>

typedef __bf16 bf16;
typedef __bf16 bf16x8 __attribute__((ext_vector_type(8)));
typedef __bf16 bf16x4 __attribute__((ext_vector_type(4)));
typedef float f32x4 __attribute__((ext_vector_type(4)));

#define NROW 8192
#define BHALF 4096
#define DFE 2048
#define DP 256
#define NCLS 1000

#define LOGITS_N 8191
#define OUT_LOGITS 2
#define OUT_LABELS (2 + 8192 * 8191)
#define OUT_LIDS32 (OUT_LABELS + 8192)
#define OUT_LIDS512 (OUT_LIDS32 + 8192)

// ---------------- init: zero scalar accumulators + write labels ----------------
__global__ __launch_bounds__(256) void init_kernel(float* out) {
    int i = blockIdx.x * 256 + threadIdx.x;
    if (i < 2) out[i] = 0.f;
    if (i < NROW) out[(size_t)OUT_LABELS + i] = (float)(i & (BHALF - 1));
}

// ---------------- split fe into bf16 hi/lo + row norms ----------------
__global__ __launch_bounds__(256) void split_fe_kernel(const float* __restrict__ fe0,
                                                       const float* __restrict__ fe1,
                                                       bf16* __restrict__ feh,
                                                       bf16* __restrict__ fel,
                                                       float* __restrict__ norms) {
    int row = blockIdx.x, tid = threadIdx.x;
    const float* src = (row < BHALF) ? fe0 + (size_t)row * DFE
                                     : fe1 + (size_t)(row - BHALF) * DFE;
    float ss = 0.f;
#pragma unroll
    for (int pass = 0; pass < 2; ++pass) {
        int c = (pass * 256 + tid) * 4;
        float4 v = *(const float4*)(src + c);
        ss += v.x * v.x + v.y * v.y + v.z * v.z + v.w * v.w;
        bf16 h0 = (bf16)v.x, h1 = (bf16)v.y, h2 = (bf16)v.z, h3 = (bf16)v.w;
        bf16 l0 = (bf16)(v.x - (float)h0), l1 = (bf16)(v.y - (float)h1);
        bf16 l2 = (bf16)(v.z - (float)h2), l3 = (bf16)(v.w - (float)h3);
        bf16x4 hv = {h0, h1, h2, h3};
        bf16x4 lv = {l0, l1, l2, l3};
        *(bf16x4*)(feh + (size_t)row * DFE + c) = hv;
        *(bf16x4*)(fel + (size_t)row * DFE + c) = lv;
    }
#pragma unroll
    for (int off = 32; off; off >>= 1) ss += __shfl_down(ss, off);
    __shared__ float red[4];
    if ((tid & 63) == 0) red[tid >> 6] = ss;
    __syncthreads();
    if (tid == 0) norms[row] = red[0] + red[1] + red[2] + red[3];
}

// ---------------- l2-normalize p, split into bf16 hi/lo ----------------
__global__ __launch_bounds__(256) void norm_split_p_kernel(const float* __restrict__ p0,
                                                           const float* __restrict__ p1,
                                                           bf16* __restrict__ oh,
                                                           bf16* __restrict__ ol) {
    int row = blockIdx.x, tid = threadIdx.x;
    const float* src = (row < BHALF) ? p0 + (size_t)row * DP
                                     : p1 + (size_t)(row - BHALF) * DP;
    float x = src[tid];
    float ss = x * x;
#pragma unroll
    for (int off = 32; off; off >>= 1) ss += __shfl_down(ss, off);
    __shared__ float red[4];
    if ((tid & 63) == 0) red[tid >> 6] = ss;
    __syncthreads();
    float tot = red[0] + red[1] + red[2] + red[3];
    float rn = 1.f / fmaxf(sqrtf(tot), 1e-12f);
    float o = x * rn;
    bf16 h = (bf16)o;
    bf16 l = (bf16)(o - (float)h);
    oh[(size_t)row * DP + tid] = h;
    ol[(size_t)row * DP + tid] = l;
}

// ---------------- BYOL main loss ----------------
__device__ inline float dot4(float4 a, float4 b) {
    return a.x * b.x + a.y * b.y + a.z * b.z + a.w * b.w;
}

__global__ __launch_bounds__(256) void byol_kernel(const float* __restrict__ p0,
                                                   const float* __restrict__ p1,
                                                   const float* __restrict__ z0,
                                                   const float* __restrict__ z1,
                                                   float* out) {
    int tid = threadIdx.x, wave = tid >> 6, lane = tid & 63;
    int row = blockIdx.x * 4 + wave;
    size_t base = (size_t)row * DP + lane * 4;
    float4 a0 = *(const float4*)(p0 + base);
    float4 b0 = *(const float4*)(z1 + base);
    float4 a1 = *(const float4*)(p1 + base);
    float4 b1 = *(const float4*)(z0 + base);
    float pp0 = dot4(a0, a0), zz0 = dot4(b0, b0), pz0 = dot4(a0, b0);
    float pp1 = dot4(a1, a1), zz1 = dot4(b1, b1), pz1 = dot4(a1, b1);
#pragma unroll
    for (int off = 32; off; off >>= 1) {
        pp0 += __shfl_down(pp0, off); zz0 += __shfl_down(zz0, off); pz0 += __shfl_down(pz0, off);
        pp1 += __shfl_down(pp1, off); zz1 += __shfl_down(zz1, off); pz1 += __shfl_down(pz1, off);
    }
    __shared__ float red[4];
    if (lane == 0) {
        float c0 = pz0 / (fmaxf(sqrtf(pp0), 1e-12f) * fmaxf(sqrtf(zz0), 1e-12f));
        float c1 = pz1 / (fmaxf(sqrtf(pp1), 1e-12f) * fmaxf(sqrtf(zz1), 1e-12f));
        red[wave] = (2.f - 2.f * c0) + (2.f - 2.f * c1);
    }
    __syncthreads();
    if (tid == 0) atomicAdd(out, (red[0] + red[1] + red[2] + red[3]) * (1.f / 4096.f));
}

// ---------------- online linear-probe CE loss ----------------
__global__ __launch_bounds__(256) void online_kernel(const float* __restrict__ cls0,
                                                     const float* __restrict__ cls1,
                                                     const int* __restrict__ labels,
                                                     float* out) {
    int tid = threadIdx.x, wave = tid >> 6, lane = tid & 63;
    int row = blockIdx.x * 4 + wave;
    const float* src = (row < BHALF) ? cls0 + (size_t)row * NCLS
                                     : cls1 + (size_t)(row - BHALF) * NCLS;
    int lbl = labels[row & (BHALF - 1)];
    float xs[16];
    float mx = -INFINITY;
#pragma unroll
    for (int j = 0; j < 16; ++j) {
        int c = lane + j * 64;
        xs[j] = (c < NCLS) ? src[c] : -INFINITY;
        mx = fmaxf(mx, xs[j]);
    }
#pragma unroll
    for (int off = 32; off; off >>= 1) mx = fmaxf(mx, __shfl_xor(mx, off));
    float se = 0.f;
#pragma unroll
    for (int j = 0; j < 16; ++j) se += expf(xs[j] - mx);
#pragma unroll
    for (int off = 32; off; off >>= 1) se += __shfl_xor(se, off);
    __shared__ float red[4];
    if (lane == 0) red[wave] = src[lbl] - mx - logf(se);
    __syncthreads();
    if (tid == 0) atomicAdd(out + 1, -(red[0] + red[1] + red[2] + red[3]) * (1.f / 8192.f));
}

// ---------------- split-bf16 Gram GEMM: C = X Xt via (HH + LH + HL) ----------------
// mode 0: d2 = norms[r] + norms[c] - 2*G, upper-triangle tiles only
// mode 1: logits scatter epilogue (remove-diag layout)
__global__ __launch_bounds__(256) void gemm_kernel(const bf16* __restrict__ Hp,
                                                   const bf16* __restrict__ Lp,
                                                   int K, int mode,
                                                   const float* __restrict__ norms,
                                                   float* __restrict__ d2,
                                                   float* __restrict__ outlog) {
    int bx = blockIdx.x;
    int tm = bx & 63, tn = bx >> 6;
    if (mode == 0 && tm > tn) return;  // symmetric: compute upper triangle only
    __shared__ bf16 As[128][72];  // +8 pad: 144B row stride, 16B aligned, 2-way bank max
    __shared__ bf16 Bs[128][72];
    int tid = threadIdx.x;
    int wave = tid >> 6, lane = tid & 63;
    int wr = wave >> 1, wc = wave & 1;
    int lrow = lane & 15, lquad = lane >> 4;
    f32x4 acc[4][4];
    f32x4 zz = {0.f, 0.f, 0.f, 0.f};
#pragma unroll
    for (int i = 0; i < 4; ++i)
#pragma unroll
        for (int j = 0; j < 4; ++j) acc[i][j] = zz;

    for (int chunk = 0; chunk < 3; ++chunk) {
        const bf16* Ab = (chunk == 1) ? Lp : Hp;
        const bf16* Bb = (chunk == 2) ? Lp : Hp;
        const bf16* Aptr = Ab + (size_t)tm * 128 * K;
        const bf16* Bptr = Bb + (size_t)tn * 128 * K;
        for (int k0 = 0; k0 < K; k0 += 64) {
#pragma unroll
            for (int it = 0; it < 4; ++it) {
                int idx = it * 256 + tid;
                int r = idx >> 3, c8 = (idx & 7) << 3;
                *(uint4*)(&As[r][c8]) = *(const uint4*)(Aptr + (size_t)r * K + (k0 + c8));
                *(uint4*)(&Bs[r][c8]) = *(const uint4*)(Bptr + (size_t)r * K + (k0 + c8));
            }
            __syncthreads();
#pragma unroll
            for (int ks = 0; ks < 64; ks += 32) {
                bf16x8 af[4], bfr[4];
#pragma unroll
                for (int t = 0; t < 4; ++t)
                    af[t] = *(const bf16x8*)(&As[wr * 64 + t * 16 + lrow][ks + lquad * 8]);
#pragma unroll
                for (int t = 0; t < 4; ++t)
                    bfr[t] = *(const bf16x8*)(&Bs[wc * 64 + t * 16 + lrow][ks + lquad * 8]);
#pragma unroll
                for (int i = 0; i < 4; ++i)
#pragma unroll
                    for (int j = 0; j < 4; ++j)
                        acc[i][j] = __builtin_amdgcn_mfma_f32_16x16x32_bf16(af[i], bfr[j], acc[i][j], 0, 0, 0);
            }
            __syncthreads();
        }
    }

    int rowbase = tm * 128 + wr * 64;
    int colbase = tn * 128 + wc * 64;
    if (mode == 0) {
#pragma unroll
        for (int i = 0; i < 4; ++i) {
#pragma unroll
            for (int e = 0; e < 4; ++e) {
                int grow = rowbase + i * 16 + lquad * 4 + e;
                float na = norms[grow];
#pragma unroll
                for (int j = 0; j < 4; ++j) {
                    int gcol = colbase + j * 16 + lrow;
                    float v = na + norms[gcol] - 2.f * acc[i][j][e];
                    d2[(size_t)grow * NROW + gcol] = fmaxf(v, 0.f);
                }
            }
        }
    } else {
#pragma unroll
        for (int i = 0; i < 4; ++i) {
#pragma unroll
            for (int j = 0; j < 4; ++j) {
#pragma unroll
                for (int e = 0; e < 4; ++e) {
                    int r = rowbase + i * 16 + lquad * 4 + e;
                    int c = colbase + j * 16 + lrow;
                    int oc = 0;
                    bool skip = false;
                    if (r < BHALF) {
                        if (c >= BHALF) oc = c - BHALF;           // l01 block
                        else if (c == r) skip = true;             // diag of l00
                        else oc = BHALF + (c < r ? c : c - 1);    // l00 nodiag
                    } else {
                        int rp = r - BHALF;
                        if (c < BHALF) oc = c;                    // l10 block
                        else {
                            int cp = c - BHALF;
                            if (cp == rp) skip = true;            // diag of l11
                            else oc = BHALF + (cp < rp ? cp : cp - 1);
                        }
                    }
                    if (!skip) outlog[(size_t)r * LOGITS_N + oc] = acc[i][j][e];
                }
            }
        }
    }
}

// ---------------- mirror upper triangle of D2 into lower ----------------
__global__ __launch_bounds__(256) void mirror_kernel(float* __restrict__ d2) {
    int bj = blockIdx.x, bi = blockIdx.y;
    if (bi < bj) return;  // only lower-left (incl diagonal) blocks write
    __shared__ float t[32][33];
    int tx = threadIdx.x & 31, ty = threadIdx.x >> 5;  // 32 x 8
#pragma unroll
    for (int r = 0; r < 32; r += 8)
        t[r + ty][tx] = d2[(size_t)(bj * 32 + r + ty) * NROW + bi * 32 + tx];
    __syncthreads();
#pragma unroll
    for (int r = 0; r < 32; r += 8) {
        int gi = bi * 32 + r + ty, gj = bj * 32 + tx;
        if (gi > gj) d2[(size_t)gi * NROW + gj] = t[tx][r + ty];
    }
}

// ---------------- exact rank-32 / rank-512 select + LID per row ----------------
__global__ __launch_bounds__(256) void select_kernel(const float* __restrict__ d2,
                                                     float* __restrict__ out) {
    int row = blockIdx.x, tid = threadIdx.x;
    int lane = tid & 63, wave = tid >> 6;
    const float* drow = d2 + (size_t)row * NROW;
    unsigned v[32];
#pragma unroll
    for (int j = 0; j < 32; ++j) {
        int c = j * 256 + tid;
        float f = drow[c];
        v[j] = (c == row) ? 0xFFFFFFFFu : __float_as_uint(f);  // exclude self
    }
    __shared__ unsigned redu[8];
    __shared__ unsigned dec;
    unsigned p1 = 0, p2 = 0;  // rank-32 / rank-512 bit patterns under construction
    for (int bit = 31; bit >= 0; --bit) {
        unsigned c1 = p1 | (1u << bit), c2 = p2 | (1u << bit);
        unsigned n1 = 0, n2 = 0;
#pragma unroll
        for (int j = 0; j < 32; ++j) { n1 += (v[j] < c1); n2 += (v[j] < c2); }
#pragma unroll
        for (int off = 32; off; off >>= 1) {
            n1 += __shfl_down(n1, off);
            n2 += __shfl_down(n2, off);
        }
        if (lane == 0) { redu[wave * 2] = n1; redu[wave * 2 + 1] = n2; }
        __syncthreads();
        if (tid == 0) {
            unsigned t1 = redu[0] + redu[2] + redu[4] + redu[6];
            unsigned t2 = redu[1] + redu[3] + redu[5] + redu[7];
            dec = ((t1 < 32u) ? 1u : 0u) | ((t2 < 512u) ? 2u : 0u);
        }
        __syncthreads();
        unsigned d = dec;
        if (d & 1u) p1 = c1;
        if (d & 2u) p2 = c2;
    }
    // final: sum of log(d_i/d_k + eps) over strictly-smaller values (ties -> log1 = 0)
    float dk1 = sqrtf(__uint_as_float(p1));
    float dk2 = sqrtf(__uint_as_float(p2));
    float s1 = 0.f, s2 = 0.f;
#pragma unroll
    for (int j = 0; j < 32; ++j) {
        unsigned b = v[j];
        if (b < p2) {
            float d = sqrtf(__uint_as_float(b));
            s2 += logf(d / dk2 + 1e-12f);
            if (b < p1) s1 += logf(d / dk1 + 1e-12f);
        }
    }
#pragma unroll
    for (int off = 32; off; off >>= 1) {
        s1 += __shfl_down(s1, off);
        s2 += __shfl_down(s2, off);
    }
    __shared__ float redf[8];
    if (lane == 0) { redf[wave * 2] = s1; redf[wave * 2 + 1] = s2; }
    __syncthreads();
    if (tid == 0) {
        float t1 = redf[0] + redf[2] + redf[4] + redf[6];
        float t2 = redf[1] + redf[3] + redf[5] + redf[7];
        out[(size_t)OUT_LIDS32 + row] = -32.f / t1;
        out[(size_t)OUT_LIDS512 + row] = -512.f / t2;
    }
}

extern "C" void kernel_launch(void* const* d_in, const int* in_sizes, int n_in,
                              void* d_out, int out_size, void* d_ws, size_t ws_size,
                              hipStream_t stream) {
    const float* fe0 = (const float*)d_in[0];
    const float* fe1 = (const float*)d_in[1];
    const float* p0 = (const float*)d_in[2];
    const float* p1 = (const float*)d_in[3];
    const float* z0 = (const float*)d_in[4];
    const float* z1 = (const float*)d_in[5];
    const float* cls0 = (const float*)d_in[6];
    const float* cls1 = (const float*)d_in[7];
    const int* labels = (const int*)d_in[8];
    float* out = (float*)d_out;

    // workspace layout (total ~344 MB)
    char* ws = (char*)d_ws;
    float* D2 = (float*)ws;                                        // 268435456 B
    bf16* FEH = (bf16*)(ws + 268435456UL);                         // 33554432 B
    bf16* FEL = (bf16*)(ws + 268435456UL + 33554432UL);            // 33554432 B
    bf16* OH = (bf16*)(ws + 268435456UL + 2 * 33554432UL);         // 4194304 B
    bf16* OL = (bf16*)(ws + 268435456UL + 2 * 33554432UL + 4194304UL);  // 4194304 B
    float* NORMS = (float*)(ws + 268435456UL + 2 * 33554432UL + 2 * 4194304UL);  // 32 KB

    init_kernel<<<32, 256, 0, stream>>>(out);
    split_fe_kernel<<<8192, 256, 0, stream>>>(fe0, fe1, FEH, FEL, NORMS);
    norm_split_p_kernel<<<8192, 256, 0, stream>>>(p0, p1, OH, OL);
    byol_kernel<<<1024, 256, 0, stream>>>(p0, p1, z0, z1, out);
    online_kernel<<<2048, 256, 0, stream>>>(cls0, cls1, labels, out);
    gemm_kernel<<<4096, 256, 0, stream>>>(FEH, FEL, DFE, 0, NORMS, D2, nullptr);
    mirror_kernel<<<dim3(256, 256), 256, 0, stream>>>(D2);
    select_kernel<<<8192, 256, 0, stream>>>(D2, out);
    gemm_kernel<<<4096, 256, 0, stream>>>(OH, OL, DP, 1, nullptr, nullptr, out + OUT_LOGITS);
}

// Round 2
// 1319.435 us; speedup vs baseline: 1.1903x; 1.1903x over previous
//
#include <hip/hip_runtime.h>
#include <math.h>

typedef __bf16 bf16;
typedef __bf16 bf16x8 __attribute__((ext_vector_type(8)));
typedef __bf16 bf16x4 __attribute__((ext_vector_type(4)));
typedef float f32x4 __attribute__((ext_vector_type(4)));

#define NROW 8192
#define BHALF 4096
#define DFE 2048
#define DP 256
#define NCLS 1000

#define LOGITS_N 8191
#define OUT_LOGITS 2
#define OUT_LABELS (2 + 8192 * 8191)
#define OUT_LIDS32 (OUT_LABELS + 8192)
#define OUT_LIDS512 (OUT_LIDS32 + 8192)

// async 16B global->LDS (dest = wave-uniform base + lane*16)
__device__ inline void gload16(const bf16* g, bf16* l) {
    __builtin_amdgcn_global_load_lds((const __attribute__((address_space(1))) void*)g,
                                     (__attribute__((address_space(3))) void*)l, 16, 0, 0);
}

// ---------------- init: zero scalar accumulators + write labels ----------------
__global__ __launch_bounds__(256) void init_kernel(float* out) {
    int i = blockIdx.x * 256 + threadIdx.x;
    if (i < 2) out[i] = 0.f;
    if (i < NROW) out[(size_t)OUT_LABELS + i] = (float)(i & (BHALF - 1));
}

// ---------------- split fe into bf16 hi/lo + row norms ----------------
__global__ __launch_bounds__(256) void split_fe_kernel(const float* __restrict__ fe0,
                                                       const float* __restrict__ fe1,
                                                       bf16* __restrict__ feh,
                                                       bf16* __restrict__ fel,
                                                       float* __restrict__ norms) {
    int row = blockIdx.x, tid = threadIdx.x;
    const float* src = (row < BHALF) ? fe0 + (size_t)row * DFE
                                     : fe1 + (size_t)(row - BHALF) * DFE;
    float ss = 0.f;
#pragma unroll
    for (int pass = 0; pass < 2; ++pass) {
        int c = (pass * 256 + tid) * 4;
        float4 v = *(const float4*)(src + c);
        ss += v.x * v.x + v.y * v.y + v.z * v.z + v.w * v.w;
        bf16 h0 = (bf16)v.x, h1 = (bf16)v.y, h2 = (bf16)v.z, h3 = (bf16)v.w;
        bf16 l0 = (bf16)(v.x - (float)h0), l1 = (bf16)(v.y - (float)h1);
        bf16 l2 = (bf16)(v.z - (float)h2), l3 = (bf16)(v.w - (float)h3);
        bf16x4 hv = {h0, h1, h2, h3};
        bf16x4 lv = {l0, l1, l2, l3};
        *(bf16x4*)(feh + (size_t)row * DFE + c) = hv;
        *(bf16x4*)(fel + (size_t)row * DFE + c) = lv;
    }
#pragma unroll
    for (int off = 32; off; off >>= 1) ss += __shfl_down(ss, off);
    __shared__ float red[4];
    if ((tid & 63) == 0) red[tid >> 6] = ss;
    __syncthreads();
    if (tid == 0) norms[row] = red[0] + red[1] + red[2] + red[3];
}

// ---------------- l2-normalize p -> bf16 (HH-only logits path) ----------------
__global__ __launch_bounds__(256) void norm_split_p_kernel(const float* __restrict__ p0,
                                                           const float* __restrict__ p1,
                                                           bf16* __restrict__ oh) {
    int row = blockIdx.x, tid = threadIdx.x;
    const float* src = (row < BHALF) ? p0 + (size_t)row * DP
                                     : p1 + (size_t)(row - BHALF) * DP;
    float x = src[tid];
    float ss = x * x;
#pragma unroll
    for (int off = 32; off; off >>= 1) ss += __shfl_down(ss, off);
    __shared__ float red[4];
    if ((tid & 63) == 0) red[tid >> 6] = ss;
    __syncthreads();
    float tot = red[0] + red[1] + red[2] + red[3];
    float rn = 1.f / fmaxf(sqrtf(tot), 1e-12f);
    oh[(size_t)row * DP + tid] = (bf16)(x * rn);
}

// ---------------- BYOL main loss ----------------
__device__ inline float dot4(float4 a, float4 b) {
    return a.x * b.x + a.y * b.y + a.z * b.z + a.w * b.w;
}

__global__ __launch_bounds__(256) void byol_kernel(const float* __restrict__ p0,
                                                   const float* __restrict__ p1,
                                                   const float* __restrict__ z0,
                                                   const float* __restrict__ z1,
                                                   float* out) {
    int tid = threadIdx.x, wave = tid >> 6, lane = tid & 63;
    int row = blockIdx.x * 4 + wave;
    size_t base = (size_t)row * DP + lane * 4;
    float4 a0 = *(const float4*)(p0 + base);
    float4 b0 = *(const float4*)(z1 + base);
    float4 a1 = *(const float4*)(p1 + base);
    float4 b1 = *(const float4*)(z0 + base);
    float pp0 = dot4(a0, a0), zz0 = dot4(b0, b0), pz0 = dot4(a0, b0);
    float pp1 = dot4(a1, a1), zz1 = dot4(b1, b1), pz1 = dot4(a1, b1);
#pragma unroll
    for (int off = 32; off; off >>= 1) {
        pp0 += __shfl_down(pp0, off); zz0 += __shfl_down(zz0, off); pz0 += __shfl_down(pz0, off);
        pp1 += __shfl_down(pp1, off); zz1 += __shfl_down(zz1, off); pz1 += __shfl_down(pz1, off);
    }
    __shared__ float red[4];
    if (lane == 0) {
        float c0 = pz0 / (fmaxf(sqrtf(pp0), 1e-12f) * fmaxf(sqrtf(zz0), 1e-12f));
        float c1 = pz1 / (fmaxf(sqrtf(pp1), 1e-12f) * fmaxf(sqrtf(zz1), 1e-12f));
        red[wave] = (2.f - 2.f * c0) + (2.f - 2.f * c1);
    }
    __syncthreads();
    if (tid == 0) atomicAdd(out, (red[0] + red[1] + red[2] + red[3]) * (1.f / 4096.f));
}

// ---------------- online linear-probe CE loss ----------------
__global__ __launch_bounds__(256) void online_kernel(const float* __restrict__ cls0,
                                                     const float* __restrict__ cls1,
                                                     const int* __restrict__ labels,
                                                     float* out) {
    int tid = threadIdx.x, wave = tid >> 6, lane = tid & 63;
    int row = blockIdx.x * 4 + wave;
    const float* src = (row < BHALF) ? cls0 + (size_t)row * NCLS
                                     : cls1 + (size_t)(row - BHALF) * NCLS;
    int lbl = labels[row & (BHALF - 1)];
    float xs[16];
    float mx = -INFINITY;
#pragma unroll
    for (int j = 0; j < 16; ++j) {
        int c = lane + j * 64;
        xs[j] = (c < NCLS) ? src[c] : -INFINITY;
        mx = fmaxf(mx, xs[j]);
    }
#pragma unroll
    for (int off = 32; off; off >>= 1) mx = fmaxf(mx, __shfl_xor(mx, off));
    float se = 0.f;
#pragma unroll
    for (int j = 0; j < 16; ++j) se += expf(xs[j] - mx);
#pragma unroll
    for (int off = 32; off; off >>= 1) se += __shfl_xor(se, off);
    __shared__ float red[4];
    if (lane == 0) red[wave] = src[lbl] - mx - logf(se);
    __syncthreads();
    if (tid == 0) atomicAdd(out + 1, -(red[0] + red[1] + red[2] + red[3]) * (1.f / 8192.f));
}

// ---------------- m97-style split-bf16 Gram GEMM ----------------
// mode 0: d2 = norms[r]+norms[c]-2*G, upper-triangle tiles (nchunks=3: HH+LH+HL)
// mode 1: logits scatter epilogue (nchunks=1: HH only)
// LDS: unpadded [128][64] bf16 tiles, XOR-swizzled (phys_grp = log_grp ^ (row&7))
// staged via global_load_lds width-16 (dest = wave base + lane*16).
__global__ __launch_bounds__(256) void gemm_kernel(const bf16* __restrict__ Hp,
                                                   const bf16* __restrict__ Lp,
                                                   int K, int nchunks, int mode,
                                                   const float* __restrict__ norms,
                                                   float* __restrict__ d2,
                                                   float* __restrict__ outlog) {
    __shared__ bf16 As[128 * 64];
    __shared__ bf16 Bs[128 * 64];
    int tid = threadIdx.x, lane = tid & 63, wave = tid >> 6;
    int tm, tn;
    if (mode == 0) {
        int L = blockIdx.x;
        int t = (int)((sqrtf(8.f * (float)L + 1.f) - 1.f) * 0.5f);
        while ((t + 1) * (t + 2) / 2 <= L) ++t;
        while (t * (t + 1) / 2 > L) --t;
        tn = t;
        tm = L - t * (t + 1) / 2;  // 0 <= tm <= tn <= 63
    } else {
        tm = blockIdx.x & 63;
        tn = blockIdx.x >> 6;
    }

    int wr = wave >> 1, wc = wave & 1;
    int lrow = lane & 15, lquad = lane >> 4, r7 = lrow & 7;

    // staging lane geometry: lane covers row octet rsub, phys group grp
    int rsub = lane >> 3;       // 0..7
    int grp = lane & 7;         // 0..7 (phys group written by DMA)
    int lg = grp ^ rsub;        // logical k-group to fetch (swizzle baked into fetch)

    // fragment LDS byte offsets (k0-invariant; ks=32 is ^64)
    int aoff[4], boff[4];
#pragma unroll
    for (int t = 0; t < 4; ++t) {
        aoff[t] = (((wr * 64 + t * 16 + lrow) * 64) + (lquad ^ r7) * 8) * 2;
        boff[t] = (((wc * 64 + t * 16 + lrow) * 64) + (lquad ^ r7) * 8) * 2;
    }
    const char* Asb = (const char*)As;
    const char* Bsb = (const char*)Bs;

    f32x4 acc[4][4];
    f32x4 zz = {0.f, 0.f, 0.f, 0.f};
#pragma unroll
    for (int i = 0; i < 4; ++i)
#pragma unroll
        for (int j = 0; j < 4; ++j) acc[i][j] = zz;

    bf16* Al = As + wave * 32 * 64;
    bf16* Bl = Bs + wave * 32 * 64;

    for (int chunk = 0; chunk < nchunks; ++chunk) {
        const bf16* Ab = (chunk == 1) ? Lp : Hp;
        const bf16* Bb = (chunk == 2) ? Lp : Hp;
        const bf16* Ag = Ab + (size_t)(tm * 128 + wave * 32 + rsub) * K + lg * 8;
        const bf16* Bg = Bb + (size_t)(tn * 128 + wave * 32 + rsub) * K + lg * 8;
        for (int k0 = 0; k0 < K; k0 += 64) {
#pragma unroll
            for (int t = 0; t < 4; ++t) {
                gload16(Ag + (size_t)t * 8 * K + k0, Al + t * 8 * 64);
                gload16(Bg + (size_t)t * 8 * K + k0, Bl + t * 8 * 64);
            }
            __syncthreads();
#pragma unroll
            for (int ks = 0; ks < 2; ++ks) {
                bf16x8 af[4], bf_[4];
#pragma unroll
                for (int t = 0; t < 4; ++t) af[t] = *(const bf16x8*)(Asb + (aoff[t] ^ (ks * 64)));
#pragma unroll
                for (int t = 0; t < 4; ++t) bf_[t] = *(const bf16x8*)(Bsb + (boff[t] ^ (ks * 64)));
#pragma unroll
                for (int i = 0; i < 4; ++i)
#pragma unroll
                    for (int j = 0; j < 4; ++j)
                        acc[i][j] = __builtin_amdgcn_mfma_f32_16x16x32_bf16(af[i], bf_[j], acc[i][j], 0, 0, 0);
            }
            __syncthreads();
        }
    }

    int rowbase = tm * 128 + wr * 64;
    int colbase = tn * 128 + wc * 64;
    if (mode == 0) {
#pragma unroll
        for (int i = 0; i < 4; ++i) {
#pragma unroll
            for (int e = 0; e < 4; ++e) {
                int grow = rowbase + i * 16 + lquad * 4 + e;
                float na = norms[grow];
#pragma unroll
                for (int j = 0; j < 4; ++j) {
                    int gcol = colbase + j * 16 + lrow;
                    float v = na + norms[gcol] - 2.f * acc[i][j][e];
                    d2[(size_t)grow * NROW + gcol] = fmaxf(v, 0.f);
                }
            }
        }
    } else {
#pragma unroll
        for (int i = 0; i < 4; ++i) {
#pragma unroll
            for (int j = 0; j < 4; ++j) {
#pragma unroll
                for (int e = 0; e < 4; ++e) {
                    int r = rowbase + i * 16 + lquad * 4 + e;
                    int c = colbase + j * 16 + lrow;
                    int oc = 0;
                    bool skip = false;
                    if (r < BHALF) {
                        if (c >= BHALF) oc = c - BHALF;           // l01 block
                        else if (c == r) skip = true;             // diag of l00
                        else oc = BHALF + (c < r ? c : c - 1);    // l00 nodiag
                    } else {
                        int rp = r - BHALF;
                        if (c < BHALF) oc = c;                    // l10 block
                        else {
                            int cp = c - BHALF;
                            if (cp == rp) skip = true;            // diag of l11
                            else oc = BHALF + (cp < rp ? cp : cp - 1);
                        }
                    }
                    if (!skip) outlog[(size_t)r * LOGITS_N + oc] = acc[i][j][e];
                }
            }
        }
    }
}

// ---------------- mirror upper triangle of D2 into lower ----------------
__global__ __launch_bounds__(256) void mirror_kernel(float* __restrict__ d2) {
    int bj = blockIdx.x, bi = blockIdx.y;
    if (bi < bj) return;  // only lower-left (incl diagonal) blocks write
    __shared__ float t[32][33];
    int tx = threadIdx.x & 31, ty = threadIdx.x >> 5;  // 32 x 8
#pragma unroll
    for (int r = 0; r < 32; r += 8)
        t[r + ty][tx] = d2[(size_t)(bj * 32 + r + ty) * NROW + bi * 32 + tx];
    __syncthreads();
#pragma unroll
    for (int r = 0; r < 32; r += 8) {
        int gi = bi * 32 + r + ty, gj = bj * 32 + tx;
        if (gi > gj) d2[(size_t)gi * NROW + gj] = t[tx][r + ty];
    }
}

// ---------------- exact rank-32 / rank-512 select + LID per row ----------------
__global__ __launch_bounds__(256) void select_kernel(const float* __restrict__ d2,
                                                     float* __restrict__ out) {
    int row = blockIdx.x, tid = threadIdx.x;
    int lane = tid & 63, wave = tid >> 6;
    const float4* drow4 = (const float4*)(d2 + (size_t)row * NROW);
    unsigned v[32];
#pragma unroll
    for (int j = 0; j < 8; ++j) {
        int idx4 = j * 256 + tid;
        float4 f = drow4[idx4];
        int c0 = idx4 * 4;
        v[j * 4 + 0] = (c0 == row) ? 0xFFFFFFFFu : __float_as_uint(f.x);
        v[j * 4 + 1] = (c0 + 1 == row) ? 0xFFFFFFFFu : __float_as_uint(f.y);
        v[j * 4 + 2] = (c0 + 2 == row) ? 0xFFFFFFFFu : __float_as_uint(f.z);
        v[j * 4 + 3] = (c0 + 3 == row) ? 0xFFFFFFFFu : __float_as_uint(f.w);
    }
    __shared__ unsigned redu[8];
    __shared__ unsigned dec;
    unsigned p1 = 0, p2 = 0;  // rank-32 / rank-512 bit patterns under construction
    for (int bit = 31; bit >= 0; --bit) {
        unsigned c1 = p1 | (1u << bit), c2 = p2 | (1u << bit);
        unsigned n1 = 0, n2 = 0;
#pragma unroll
        for (int j = 0; j < 32; ++j) { n1 += (v[j] < c1); n2 += (v[j] < c2); }
#pragma unroll
        for (int off = 32; off; off >>= 1) {
            n1 += __shfl_down(n1, off);
            n2 += __shfl_down(n2, off);
        }
        if (lane == 0) { redu[wave * 2] = n1; redu[wave * 2 + 1] = n2; }
        __syncthreads();
        if (tid == 0) {
            unsigned t1 = redu[0] + redu[2] + redu[4] + redu[6];
            unsigned t2 = redu[1] + redu[3] + redu[5] + redu[7];
            dec = ((t1 < 32u) ? 1u : 0u) | ((t2 < 512u) ? 2u : 0u);
        }
        __syncthreads();
        unsigned d = dec;
        if (d & 1u) p1 = c1;
        if (d & 2u) p2 = c2;
    }
    float dk1 = sqrtf(__uint_as_float(p1));
    float dk2 = sqrtf(__uint_as_float(p2));
    float s1 = 0.f, s2 = 0.f;
#pragma unroll
    for (int j = 0; j < 32; ++j) {
        unsigned b = v[j];
        if (b < p2) {
            float d = sqrtf(__uint_as_float(b));
            s2 += logf(d / dk2 + 1e-12f);
            if (b < p1) s1 += logf(d / dk1 + 1e-12f);
        }
    }
#pragma unroll
    for (int off = 32; off; off >>= 1) {
        s1 += __shfl_down(s1, off);
        s2 += __shfl_down(s2, off);
    }
    __shared__ float redf[8];
    if (lane == 0) { redf[wave * 2] = s1; redf[wave * 2 + 1] = s2; }
    __syncthreads();
    if (tid == 0) {
        float t1 = redf[0] + redf[2] + redf[4] + redf[6];
        float t2 = redf[1] + redf[3] + redf[5] + redf[7];
        out[(size_t)OUT_LIDS32 + row] = -32.f / t1;
        out[(size_t)OUT_LIDS512 + row] = -512.f / t2;
    }
}

extern "C" void kernel_launch(void* const* d_in, const int* in_sizes, int n_in,
                              void* d_out, int out_size, void* d_ws, size_t ws_size,
                              hipStream_t stream) {
    const float* fe0 = (const float*)d_in[0];
    const float* fe1 = (const float*)d_in[1];
    const float* p0 = (const float*)d_in[2];
    const float* p1 = (const float*)d_in[3];
    const float* z0 = (const float*)d_in[4];
    const float* z1 = (const float*)d_in[5];
    const float* cls0 = (const float*)d_in[6];
    const float* cls1 = (const float*)d_in[7];
    const int* labels = (const int*)d_in[8];
    float* out = (float*)d_out;

    // workspace layout
    char* ws = (char*)d_ws;
    float* D2 = (float*)ws;                                        // 268435456 B
    bf16* FEH = (bf16*)(ws + 268435456UL);                         // 33554432 B
    bf16* FEL = (bf16*)(ws + 268435456UL + 33554432UL);            // 33554432 B
    bf16* OH = (bf16*)(ws + 268435456UL + 2 * 33554432UL);         // 4194304 B
    float* NORMS = (float*)(ws + 268435456UL + 2 * 33554432UL + 4194304UL);  // 32 KB

    init_kernel<<<32, 256, 0, stream>>>(out);
    split_fe_kernel<<<8192, 256, 0, stream>>>(fe0, fe1, FEH, FEL, NORMS);
    norm_split_p_kernel<<<8192, 256, 0, stream>>>(p0, p1, OH);
    byol_kernel<<<1024, 256, 0, stream>>>(p0, p1, z0, z1, out);
    online_kernel<<<2048, 256, 0, stream>>>(cls0, cls1, labels, out);
    gemm_kernel<<<2080, 256, 0, stream>>>(FEH, FEL, DFE, 3, 0, NORMS, D2, nullptr);
    mirror_kernel<<<dim3(256, 256), 256, 0, stream>>>(D2);
    select_kernel<<<8192, 256, 0, stream>>>(D2, out);
    gemm_kernel<<<4096, 256, 0, stream>>>(OH, OH, DP, 1, 1, nullptr, nullptr, out + OUT_LOGITS);
}